// Round 10
// baseline (386.732 us; speedup 1.0000x reference)
//
#include <hip/hip_runtime.h>
#include <hip/hip_bf16.h>
#include <math.h>

// Problem constants (fixed by setup_inputs)
#define B  4
#define P  5000
#define NPT 100
#define F  64          // pointnet feature dim
#define NX 240
#define NY 240
#define C1 128         // conv1/conv2 out channels

typedef __attribute__((ext_vector_type(8)))  short short8;   // 8 bf16
typedef __attribute__((ext_vector_type(16))) float f32x16;

// tanh via v_exp + v_rcp (rel err ~1e-6; saturates correctly at +-1)
__device__ __forceinline__ float tanh_fast(float x) {
    float e = __expf(2.0f * x);
    float r = __builtin_amdgcn_rcpf(e + 1.0f);
    return __builtin_fmaf(-2.0f, r, 1.0f);
}
__device__ __forceinline__ short bf16_bits(float f) {
    return (short)(__bfloat16_as_ushort(__float2bfloat16(f)));
}

// ---------------------------------------------------------------------------
// PointNet, both layers on MFMA (unchanged from R8).
// ---------------------------------------------------------------------------
__global__ __launch_bounds__(128) void pn_mfma_kernel(
    const float* __restrict__ pillars,    // [B,P,N,8]
    const short* __restrict__ w0p,        // [4 slots][64 n][8 k] bf16 bits
    const float* __restrict__ b0,         // [64]
    const __hip_bfloat16* __restrict__ w1t, // [64n][64k] bf16
    const float* __restrict__ b1,         // [64]
    float* __restrict__ pmax)             // [B*P,64]
{
    constexpr int HS = F + 8;             // 72 shorts
    constexpr int XS = 40;                // 80B row: bank stride 20 -> max 4-way
    __shared__ short xA[128 * XS];
    __shared__ short hA[128 * HS];
    __shared__ float red[2][F];
    __shared__ unsigned int vb32[4];

    int bp = blockIdx.x;
    int n  = threadIdx.x;
    int wave = n >> 6, lane = n & 63;
    int mr = lane & 31;
    int g  = lane >> 5;
    bool live = (n < NPT);

    const float* xp = pillars + ((size_t)bp * NPT + (live ? n : 0)) * 8;
    float4 q0 = *(const float4*)xp;
    float4 q1 = *(const float4*)(xp + 4);
    float x[8] = {q0.x, q0.y, q0.z, q0.w, q1.x, q1.y, q1.z, q1.w};

    float ss = 0.f;
#pragma unroll
    for (int c = 0; c < 8; c++) ss += x[c] * x[c];
    bool valid = live && (ss < 1e12f);

    unsigned long long bal = __ballot(valid);
    if (lane == 0) {
        vb32[wave * 2]     = (unsigned)bal;
        vb32[wave * 2 + 1] = (unsigned)(bal >> 32);
    }

    short8 xhi, xlo, xz;
#pragma unroll
    for (int c = 0; c < 8; c++) {
        __hip_bfloat16 hb = __float2bfloat16(x[c]);
        float hv = __bfloat162float(hb);
        xhi[c] = (short)__bfloat16_as_ushort(hb);
        xlo[c] = bf16_bits(x[c] - hv);
        xz[c] = 0;
    }
    *(short8*)&xA[n * XS + 0]  = xhi;
    *(short8*)&xA[n * XS + 8]  = xlo;
    *(short8*)&xA[n * XS + 16] = xhi;
    *(short8*)&xA[n * XS + 24] = xz;
    __syncthreads();

    short8 wb[2][2];   // [kk][nt]
#pragma unroll
    for (int kk = 0; kk < 2; kk++)
#pragma unroll
        for (int nt = 0; nt < 2; nt++)
            wb[kk][nt] = *(const short8*)(w0p + ((kk * 2 + g) * 64 + nt * 32 + mr) * 8);

    f32x16 hc00 = {0,0,0,0,0,0,0,0,0,0,0,0,0,0,0,0};
    f32x16 hc01 = hc00, hc10 = hc00, hc11 = hc00;
#pragma unroll
    for (int kk = 0; kk < 2; kk++) {
        short8 a0 = *(const short8*)&xA[(wave * 64 + mr) * XS + kk * 16 + g * 8];
        short8 a1 = *(const short8*)&xA[(wave * 64 + 32 + mr) * XS + kk * 16 + g * 8];
        hc00 = __builtin_amdgcn_mfma_f32_32x32x16_bf16(a0, wb[kk][0], hc00, 0, 0, 0);
        hc01 = __builtin_amdgcn_mfma_f32_32x32x16_bf16(a0, wb[kk][1], hc01, 0, 0, 0);
        hc10 = __builtin_amdgcn_mfma_f32_32x32x16_bf16(a1, wb[kk][0], hc10, 0, 0, 0);
        hc11 = __builtin_amdgcn_mfma_f32_32x32x16_bf16(a1, wb[kk][1], hc11, 0, 0, 0);
    }

    float b00 = b0[mr];
    float b01 = b0[32 + mr];
#pragma unroll
    for (int mt = 0; mt < 2; mt++) {
#pragma unroll
        for (int r = 0; r < 16; r++) {
            int prow = wave * 64 + mt * 32 + (r & 3) + 8 * (r >> 2) + 4 * g;
            float h0 = (mt == 0) ? hc00[r] : hc10[r];
            float h1 = (mt == 0) ? hc01[r] : hc11[r];
            hA[prow * HS + mr]      = bf16_bits(tanh_fast(h0 + b00));
            hA[prow * HS + 32 + mr] = bf16_bits(tanh_fast(h1 + b01));
        }
    }
    __syncthreads();

    short8 bfrag[2][4];
#pragma unroll
    for (int nt = 0; nt < 2; nt++)
#pragma unroll
        for (int c0 = 0; c0 < 4; c0++)
            bfrag[nt][c0] = *(const short8*)((const short*)w1t +
                                (nt * 32 + mr) * F + c0 * 16 + g * 8);

    f32x16 acc00 = {0,0,0,0,0,0,0,0,0,0,0,0,0,0,0,0};
    f32x16 acc01 = acc00, acc10 = acc00, acc11 = acc00;

    const short* arow = &hA[(wave * 64 + mr) * HS + g * 8];
#pragma unroll
    for (int c0 = 0; c0 < 4; c0++) {
        short8 af0 = *(const short8*)(arow + c0 * 16);
        short8 af1 = *(const short8*)(arow + 32 * HS + c0 * 16);
        acc00 = __builtin_amdgcn_mfma_f32_32x32x16_bf16(af0, bfrag[0][c0], acc00, 0, 0, 0);
        acc01 = __builtin_amdgcn_mfma_f32_32x32x16_bf16(af0, bfrag[1][c0], acc01, 0, 0, 0);
        acc10 = __builtin_amdgcn_mfma_f32_32x32x16_bf16(af1, bfrag[0][c0], acc10, 0, 0, 0);
        acc11 = __builtin_amdgcn_mfma_f32_32x32x16_bf16(af1, bfrag[1][c0], acc11, 0, 0, 0);
    }

    float bv0 = b1[mr];
    float bv1 = b1[32 + mr];
    bool allv = ((vb32[0] & vb32[1] & vb32[2]) == 0xFFFFFFFFu) &&
                ((vb32[3] & 0xFu) == 0xFu);
    float mx0 = -INFINITY, mx1 = -INFINITY;

    if (allv) {
#pragma unroll
        for (int mt = 0; mt < 2; mt++) {
#pragma unroll
            for (int r = 0; r < 16; r++) {
                bool inc = !(wave == 1 && mt == 1) || (g == 0 && r < 4);
                if (inc) {
                    mx0 = fmaxf(mx0, (mt == 0) ? acc00[r] : acc10[r]);
                    mx1 = fmaxf(mx1, (mt == 0) ? acc01[r] : acc11[r]);
                }
            }
        }
        mx0 += bv0;
        mx1 += bv1;
    } else {
        unsigned wm0 = vb32[wave * 2];
        unsigned wm1 = vb32[wave * 2 + 1];
#pragma unroll
        for (int mt = 0; mt < 2; mt++) {
            unsigned wm = (mt == 0) ? wm0 : wm1;
#pragma unroll
            for (int r = 0; r < 16; r++) {
                int idx = (r & 3) + 8 * (r >> 2) + 4 * g;
                bool inc = !(wave == 1 && mt == 1) || (idx < 4);
                if (inc) {
                    bool vbit = (wm >> idx) & 1;
                    float a0 = (mt == 0) ? acc00[r] : acc10[r];
                    float a1 = (mt == 0) ? acc01[r] : acc11[r];
                    mx0 = fmaxf(mx0, vbit ? (a0 + bv0) : 0.0f);
                    mx1 = fmaxf(mx1, vbit ? (a1 + bv1) : 0.0f);
                }
            }
        }
    }
    mx0 = fmaxf(mx0, __shfl_xor(mx0, 32, 64));
    mx1 = fmaxf(mx1, __shfl_xor(mx1, 32, 64));
    if (lane < 32) { red[wave][mr] = mx0; red[wave][32 + mr] = mx1; }
    __syncthreads();
    if (n < F)
        pmax[(size_t)bp * F + n] = fmaxf(red[0][n], red[1][n]);
}

// ---------------------------------------------------------------------------
// Scatter: numpy last-write-wins via atomicMax(p) + conditional write.
// ---------------------------------------------------------------------------
__global__ __launch_bounds__(256) void winner_kernel(
    const int* __restrict__ idxs, int* __restrict__ winner)
{
    int i = blockIdx.x * 256 + threadIdx.x;
    if (i >= B * P) return;
    int ix = idxs[i * 2], iy = idxs[i * 2 + 1];
    int b = i / P, p = i % P;
    atomicMax(&winner[(b * NX + ix) * NY + iy], p);
}

__global__ __launch_bounds__(64) void scatter_kernel(
    const int* __restrict__ idxs, const int* __restrict__ winner,
    const float* __restrict__ pmax, __hip_bfloat16* __restrict__ img)
{
    int bp = blockIdx.x;
    int f = threadIdx.x;
    int ix = idxs[bp * 2], iy = idxs[bp * 2 + 1];
    int b = bp / P, p = bp % P;
    int cell = (b * NX + ix) * NY + iy;
    if (winner[cell] == p)
        img[(size_t)cell * F + f] = __float2bfloat16(pmax[(size_t)bp * F + f]);
}

// ---------------------------------------------------------------------------
// Weight converts.
// ---------------------------------------------------------------------------
__global__ __launch_bounds__(256) void cvt_w_kernel(
    const float* __restrict__ w, __hip_bfloat16* __restrict__ wt, int cin)
{
    int idx = blockIdx.x * 256 + threadIdx.x;
    int total = 9 * cin * 128;
    if (idx >= total) return;
    int co = idx % 128;
    int rest = idx / 128;
    int ci = rest % cin;
    int t  = rest / cin;
    int c0 = ci >> 4, c16 = ci & 15;
    wt[(((size_t)(t * (cin >> 4) + c0)) * 128 + co) * 16 + c16] = __float2bfloat16(w[idx]);
}

__global__ __launch_bounds__(256) void cvt_w1_kernel(
    const float* __restrict__ w1, __hip_bfloat16* __restrict__ w1t)
{
    int idx = blockIdx.x * 256 + threadIdx.x;
    if (idx >= F * F) return;
    int k = idx >> 6, nn = idx & 63;
    w1t[nn * F + k] = __float2bfloat16(w1[idx]);
}

// w0 [8,64] fp32 -> w0p [4 slots][64 n][8 j] bf16 bits.
__global__ __launch_bounds__(256) void cvt_w0p_kernel(
    const float* __restrict__ w0, short* __restrict__ w0p)
{
    int idx = blockIdx.x * 256 + threadIdx.x;
    if (idx >= 4 * 64 * 8) return;
    int j = idx & 7;
    int nn = (idx >> 3) & 63;
    int s = idx >> 9;
    float wv = w0[j * F + nn];
    __hip_bfloat16 hb = __float2bfloat16(wv);
    short out = 0;
    if (s < 2)      out = (short)__bfloat16_as_ushort(hb);
    else if (s == 2) out = bf16_bits(wv - __bfloat162float(hb));
    w0p[idx] = out;
}

// ---------------------------------------------------------------------------
// MFMA implicit-GEMM 3x3 conv, SAME, Cout=128. Occupancy-tuned:
// Block: 256 thr = 4 waves = 2 x-rows x 2 co-halves. Tile: 2x x 96y x 128co.
// Wave: 96 y (3 M-tiles) x 64 co (2 N-tiles) -> 6 f32x16 acc (96 regs).
// Weights single-buffered (8 regs) -> ~155 regs -> 3 waves/SIMD.
// LDS patch: [4 x][98 y][64 ci], UNPADDED stride 64 shorts with XOR-swizzled
// 16B granules (gran' = gran ^ (row&7)) -> 50.2 KB, 3 blocks/CU, ~0 conflicts.
// (R9 bug: read address had a spurious -g*8; fixed here.)
// CIN=128: 2 ci-passes reusing the patch; CIN=64: 1 pass.
// y-tiles y0={0,72,144}: overlap rows write identical values (benign).
// ---------------------------------------------------------------------------
template<int CIN, bool FUSE>
__global__ __launch_bounds__(256, 3) void conv_mfma(
    const __hip_bfloat16* __restrict__ in,    // [B,240,240,CIN] bf16
    const __hip_bfloat16* __restrict__ wt,    // [9][CIN/16][128][16] bf16
    const float* __restrict__ bias,           // [128]
    const float* __restrict__ w2,             // [128] (FUSE)
    const float* __restrict__ b2,             // [1]   (FUSE)
    __hip_bfloat16* __restrict__ out_bf,
    float* __restrict__ out_f)
{
    constexpr int PASSES = CIN / 64;
    constexpr int CI   = 64;              // ci per pass
    constexpr int NC16 = CI / 16;         // 4
    constexpr int ROWS = 4 * 98;          // 392 rows (x-major, y within)
    __shared__ short sP[ROWS * 64];       // 50,176 B, unpadded + swizzle
    __shared__ float sred[FUSE ? 2 : 1][2][96];

    int tid  = threadIdx.x;
    int wave = tid >> 6;
    int lane = tid & 63;
    int mr = lane & 31;
    int g  = lane >> 5;
    int coh = wave & 1;        // cout half
    int xr  = wave >> 1;       // output x-row within pair
    int x0 = blockIdx.x * 2;
    int y0 = blockIdx.y * 72;  // 0 / 72 / 144 (24-row overlap, benign)
    int b  = blockIdx.z;
    int n0 = coh * 64;

    const short* wts = (const short*)wt;

    f32x16 acc[3][2];
#pragma unroll
    for (int mt = 0; mt < 3; mt++)
#pragma unroll
        for (int nt = 0; nt < 2; nt++)
            acc[mt][nt] = (f32x16){0,0,0,0,0,0,0,0,0,0,0,0,0,0,0,0};

#pragma unroll
    for (int p = 0; p < PASSES; p++) {
        if (p) __syncthreads();

        // ---- stage pass p: [4 x][98 y][64 ci] swizzled -> LDS ----
        for (int i = 0; i < 13; i++) {
            int t = tid + i * 256;
            if (t < ROWS * 8) {
                int c8  = t & 7;
                int row = t >> 3;
                int dx = row / 98, dy = row - dx * 98;
                int gx = x0 - 1 + dx, gy = y0 - 1 + dy;
                float4 v = make_float4(0.f, 0.f, 0.f, 0.f);
                if (gx >= 0 && gx < NX && gy >= 0 && gy < NY)
                    v = *(const float4*)&in[(((size_t)b * NX + gx) * NY + gy) * CIN + p * CI + c8 * 8];
                *(float4*)&sP[row * 64 + ((c8 ^ (row & 7)) * 8)] = v;
            }
        }
        __syncthreads();

        // ---- K-loop: 9 taps of this pass, weights loaded at use ----
#pragma unroll
        for (int tap = 0; tap < 9; tap++) {
            int kh = tap / 3, kw = tap % 3;
            int rowbase = (xr + kh) * 98 + kw + mr;
            int r7 = rowbase & 7;
            const short* abase = sP + rowbase * 64;
            const short* wrow = wts + ((size_t)(tap * (CIN / 16) + p * NC16) * 128 + n0 + mr) * 16 + g * 8;
#pragma unroll
            for (int c0 = 0; c0 < NC16; c0++) {
                short8 w0f = *(const short8*)(wrow + (size_t)c0 * 2048);
                short8 w1f = *(const short8*)(wrow + (size_t)c0 * 2048 + 512);
                int goff = ((c0 * 2 + g) ^ r7) * 8;   // swizzled granule (bugfix: no -g*8)
                short8 a0 = *(const short8*)(abase + goff);
                short8 a1 = *(const short8*)(abase + 32 * 64 + goff);
                short8 a2 = *(const short8*)(abase + 64 * 64 + goff);
                acc[0][0] = __builtin_amdgcn_mfma_f32_32x32x16_bf16(a0, w0f, acc[0][0], 0, 0, 0);
                acc[0][1] = __builtin_amdgcn_mfma_f32_32x32x16_bf16(a0, w1f, acc[0][1], 0, 0, 0);
                acc[1][0] = __builtin_amdgcn_mfma_f32_32x32x16_bf16(a1, w0f, acc[1][0], 0, 0, 0);
                acc[1][1] = __builtin_amdgcn_mfma_f32_32x32x16_bf16(a1, w1f, acc[1][1], 0, 0, 0);
                acc[2][0] = __builtin_amdgcn_mfma_f32_32x32x16_bf16(a2, w0f, acc[2][0], 0, 0, 0);
                acc[2][1] = __builtin_amdgcn_mfma_f32_32x32x16_bf16(a2, w1f, acc[2][1], 0, 0, 0);
            }
        }
    }

    // ---- epilogue ----
    float bv0 = bias[n0 + mr];
    float bv1 = bias[n0 + 32 + mr];
    if (!FUSE) {
        size_t base = ((size_t)b * NX + (x0 + xr)) * NY;
#pragma unroll
        for (int mt = 0; mt < 3; mt++) {
#pragma unroll
            for (int r = 0; r < 16; r++) {
                int y = y0 + mt * 32 + (r & 3) + 8 * (r >> 2) + 4 * g;
                out_bf[(base + y) * C1 + n0 + mr]      = __float2bfloat16(tanh_fast(acc[mt][0][r] + bv0));
                out_bf[(base + y) * C1 + n0 + 32 + mr] = __float2bfloat16(tanh_fast(acc[mt][1][r] + bv1));
            }
        }
    } else {
        float w20 = w2[n0 + mr];
        float w21 = w2[n0 + 32 + mr];
#pragma unroll
        for (int mt = 0; mt < 3; mt++) {
#pragma unroll
            for (int r = 0; r < 16; r++) {
                float v = tanh_fast(acc[mt][0][r] + bv0) * w20
                        + tanh_fast(acc[mt][1][r] + bv1) * w21;
                v += __shfl_xor(v, 1, 64);
                v += __shfl_xor(v, 2, 64);
                v += __shfl_xor(v, 4, 64);
                v += __shfl_xor(v, 8, 64);
                v += __shfl_xor(v, 16, 64);
                if (mr == 0)
                    sred[coh][xr][mt * 32 + (r & 3) + 8 * (r >> 2) + 4 * g] = v;
            }
        }
        __syncthreads();
        if (tid < 192) {
            int xr2 = tid / 96;
            int yy  = tid % 96;
            float r = sred[0][xr2][yy] + sred[1][xr2][yy] + b2[0];
            out_f[((size_t)b * NX + (x0 + xr2)) * NY + (y0 + yy)] = fmaxf(r, 0.f);
        }
    }
}

// ---------------------------------------------------------------------------
extern "C" void kernel_launch(void* const* d_in, const int* in_sizes, int n_in,
                              void* d_out, int out_size, void* d_ws, size_t ws_size,
                              hipStream_t stream) {
    const float* pillars = (const float*)d_in[0];
    const int*   idxs    = (const int*)d_in[1];
    const float* pn_w0   = (const float*)d_in[4];
    const float* pn_b0   = (const float*)d_in[5];
    const float* pn_w1   = (const float*)d_in[6];
    const float* pn_b1   = (const float*)d_in[7];
    const float* cw0     = (const float*)d_in[8];
    const float* cb0     = (const float*)d_in[9];
    const float* cw1     = (const float*)d_in[10];
    const float* cb1     = (const float*)d_in[11];
    const float* cw2     = (const float*)d_in[12];
    const float* cb2     = (const float*)d_in[13];
    float* out = (float*)d_out;

    // workspace layout
    char* ws = (char*)d_ws;
    const size_t IMG_BYTES  = (size_t)B * NX * NY * F * 2;
    const size_t OUT1_BYTES = (size_t)B * NX * NY * C1 * 2;
    const size_t WIN_BYTES  = (size_t)B * NX * NY * 4;
    const size_t PMAX_BYTES = (size_t)B * P * F * 4;
    const size_t WT1_BYTES  = (size_t)9 * C1 * F * 2;
    const size_t WT2_BYTES  = (size_t)9 * C1 * C1 * 2;
    const size_t W1T_BYTES  = (size_t)F * F * 2;
    __hip_bfloat16* img  = (__hip_bfloat16*)ws;
    __hip_bfloat16* out1 = (__hip_bfloat16*)(ws + IMG_BYTES);
    int*   winner = (int*)(ws + IMG_BYTES + OUT1_BYTES);
    float* pmax   = (float*)(ws + IMG_BYTES + OUT1_BYTES + WIN_BYTES);
    __hip_bfloat16* wt1 = (__hip_bfloat16*)(ws + IMG_BYTES + OUT1_BYTES + WIN_BYTES + PMAX_BYTES);
    __hip_bfloat16* wt2 = (__hip_bfloat16*)(ws + IMG_BYTES + OUT1_BYTES + WIN_BYTES + PMAX_BYTES + WT1_BYTES);
    __hip_bfloat16* w1t = (__hip_bfloat16*)(ws + IMG_BYTES + OUT1_BYTES + WIN_BYTES + PMAX_BYTES + WT1_BYTES + WT2_BYTES);
    short* w0p = (short*)(ws + IMG_BYTES + OUT1_BYTES + WIN_BYTES + PMAX_BYTES + WT1_BYTES + WT2_BYTES + W1T_BYTES);

    hipMemsetAsync(img, 0, IMG_BYTES, stream);
    hipMemsetAsync(winner, 0xFF, WIN_BYTES, stream);   // -1

    cvt_w_kernel<<<(9 * F * C1 + 255) / 256, 256, 0, stream>>>(cw0, wt1, F);
    cvt_w_kernel<<<(9 * C1 * C1 + 255) / 256, 256, 0, stream>>>(cw1, wt2, C1);
    cvt_w1_kernel<<<(F * F + 255) / 256, 256, 0, stream>>>(pn_w1, w1t);
    cvt_w0p_kernel<<<(4 * 64 * 8 + 255) / 256, 256, 0, stream>>>(pn_w0, w0p);

    pn_mfma_kernel<<<B * P, 128, 0, stream>>>(pillars, w0p, pn_b0, w1t, pn_b1, pmax);
    winner_kernel<<<(B * P + 255) / 256, 256, 0, stream>>>(idxs, winner);
    scatter_kernel<<<B * P, 64, 0, stream>>>(idxs, winner, pmax, img);

    conv_mfma<F, false><<<dim3(NX / 2, 3, B), 256, 0, stream>>>(
        img, wt1, cb0, nullptr, nullptr, out1, nullptr);
    conv_mfma<C1, true><<<dim3(NX / 2, 3, B), 256, 0, stream>>>(
        out1, wt2, cb1, cw2, cb2, nullptr, out);
}

// Round 11
// 357.861 us; speedup vs baseline: 1.0807x; 1.0807x over previous
//
#include <hip/hip_runtime.h>
#include <hip/hip_bf16.h>
#include <math.h>

// Problem constants (fixed by setup_inputs)
#define B  4
#define P  5000
#define NPT 100
#define F  64          // pointnet feature dim
#define NX 240
#define NY 240
#define C1 128         // conv1/conv2 out channels

typedef __attribute__((ext_vector_type(8)))  short short8;   // 8 bf16
typedef __attribute__((ext_vector_type(16))) float f32x16;

// tanh via v_exp + v_rcp (rel err ~1e-6; saturates correctly at +-1)
__device__ __forceinline__ float tanh_fast(float x) {
    float e = __expf(2.0f * x);
    float r = __builtin_amdgcn_rcpf(e + 1.0f);
    return __builtin_fmaf(-2.0f, r, 1.0f);
}
__device__ __forceinline__ short bf16_bits(float f) {
    return (short)(__bfloat16_as_ushort(__float2bfloat16(f)));
}
// async 16B global->LDS: wave-uniform LDS base + lane*16
__device__ __forceinline__ void async_load16(const void* g, void* l) {
    __builtin_amdgcn_global_load_lds(
        (const __attribute__((address_space(1))) void*)g,
        (__attribute__((address_space(3))) void*)l, 16, 0, 0);
}

// ---------------------------------------------------------------------------
// PointNet, both layers on MFMA (unchanged from R8/R10).
// ---------------------------------------------------------------------------
__global__ __launch_bounds__(128) void pn_mfma_kernel(
    const float* __restrict__ pillars,    // [B,P,N,8]
    const short* __restrict__ w0p,        // [4 slots][64 n][8 k] bf16 bits
    const float* __restrict__ b0,         // [64]
    const __hip_bfloat16* __restrict__ w1t, // [64n][64k] bf16
    const float* __restrict__ b1,         // [64]
    float* __restrict__ pmax)             // [B*P,64]
{
    constexpr int HS = F + 8;             // 72 shorts
    constexpr int XS = 40;                // 80B row: bank stride 20 -> max 4-way
    __shared__ short xA[128 * XS];
    __shared__ short hA[128 * HS];
    __shared__ float red[2][F];
    __shared__ unsigned int vb32[4];

    int bp = blockIdx.x;
    int n  = threadIdx.x;
    int wave = n >> 6, lane = n & 63;
    int mr = lane & 31;
    int g  = lane >> 5;
    bool live = (n < NPT);

    const float* xp = pillars + ((size_t)bp * NPT + (live ? n : 0)) * 8;
    float4 q0 = *(const float4*)xp;
    float4 q1 = *(const float4*)(xp + 4);
    float x[8] = {q0.x, q0.y, q0.z, q0.w, q1.x, q1.y, q1.z, q1.w};

    float ss = 0.f;
#pragma unroll
    for (int c = 0; c < 8; c++) ss += x[c] * x[c];
    bool valid = live && (ss < 1e12f);

    unsigned long long bal = __ballot(valid);
    if (lane == 0) {
        vb32[wave * 2]     = (unsigned)bal;
        vb32[wave * 2 + 1] = (unsigned)(bal >> 32);
    }

    short8 xhi, xlo, xz;
#pragma unroll
    for (int c = 0; c < 8; c++) {
        __hip_bfloat16 hb = __float2bfloat16(x[c]);
        float hv = __bfloat162float(hb);
        xhi[c] = (short)__bfloat16_as_ushort(hb);
        xlo[c] = bf16_bits(x[c] - hv);
        xz[c] = 0;
    }
    *(short8*)&xA[n * XS + 0]  = xhi;
    *(short8*)&xA[n * XS + 8]  = xlo;
    *(short8*)&xA[n * XS + 16] = xhi;
    *(short8*)&xA[n * XS + 24] = xz;
    __syncthreads();

    short8 wb[2][2];   // [kk][nt]
#pragma unroll
    for (int kk = 0; kk < 2; kk++)
#pragma unroll
        for (int nt = 0; nt < 2; nt++)
            wb[kk][nt] = *(const short8*)(w0p + ((kk * 2 + g) * 64 + nt * 32 + mr) * 8);

    f32x16 hc00 = {0,0,0,0,0,0,0,0,0,0,0,0,0,0,0,0};
    f32x16 hc01 = hc00, hc10 = hc00, hc11 = hc00;
#pragma unroll
    for (int kk = 0; kk < 2; kk++) {
        short8 a0 = *(const short8*)&xA[(wave * 64 + mr) * XS + kk * 16 + g * 8];
        short8 a1 = *(const short8*)&xA[(wave * 64 + 32 + mr) * XS + kk * 16 + g * 8];
        hc00 = __builtin_amdgcn_mfma_f32_32x32x16_bf16(a0, wb[kk][0], hc00, 0, 0, 0);
        hc01 = __builtin_amdgcn_mfma_f32_32x32x16_bf16(a0, wb[kk][1], hc01, 0, 0, 0);
        hc10 = __builtin_amdgcn_mfma_f32_32x32x16_bf16(a1, wb[kk][0], hc10, 0, 0, 0);
        hc11 = __builtin_amdgcn_mfma_f32_32x32x16_bf16(a1, wb[kk][1], hc11, 0, 0, 0);
    }

    float b00 = b0[mr];
    float b01 = b0[32 + mr];
#pragma unroll
    for (int mt = 0; mt < 2; mt++) {
#pragma unroll
        for (int r = 0; r < 16; r++) {
            int prow = wave * 64 + mt * 32 + (r & 3) + 8 * (r >> 2) + 4 * g;
            float h0 = (mt == 0) ? hc00[r] : hc10[r];
            float h1 = (mt == 0) ? hc01[r] : hc11[r];
            hA[prow * HS + mr]      = bf16_bits(tanh_fast(h0 + b00));
            hA[prow * HS + 32 + mr] = bf16_bits(tanh_fast(h1 + b01));
        }
    }
    __syncthreads();

    short8 bfrag[2][4];
#pragma unroll
    for (int nt = 0; nt < 2; nt++)
#pragma unroll
        for (int c0 = 0; c0 < 4; c0++)
            bfrag[nt][c0] = *(const short8*)((const short*)w1t +
                                (nt * 32 + mr) * F + c0 * 16 + g * 8);

    f32x16 acc00 = {0,0,0,0,0,0,0,0,0,0,0,0,0,0,0,0};
    f32x16 acc01 = acc00, acc10 = acc00, acc11 = acc00;

    const short* arow = &hA[(wave * 64 + mr) * HS + g * 8];
#pragma unroll
    for (int c0 = 0; c0 < 4; c0++) {
        short8 af0 = *(const short8*)(arow + c0 * 16);
        short8 af1 = *(const short8*)(arow + 32 * HS + c0 * 16);
        acc00 = __builtin_amdgcn_mfma_f32_32x32x16_bf16(af0, bfrag[0][c0], acc00, 0, 0, 0);
        acc01 = __builtin_amdgcn_mfma_f32_32x32x16_bf16(af0, bfrag[1][c0], acc01, 0, 0, 0);
        acc10 = __builtin_amdgcn_mfma_f32_32x32x16_bf16(af1, bfrag[0][c0], acc10, 0, 0, 0);
        acc11 = __builtin_amdgcn_mfma_f32_32x32x16_bf16(af1, bfrag[1][c0], acc11, 0, 0, 0);
    }

    float bv0 = b1[mr];
    float bv1 = b1[32 + mr];
    bool allv = ((vb32[0] & vb32[1] & vb32[2]) == 0xFFFFFFFFu) &&
                ((vb32[3] & 0xFu) == 0xFu);
    float mx0 = -INFINITY, mx1 = -INFINITY;

    if (allv) {
#pragma unroll
        for (int mt = 0; mt < 2; mt++) {
#pragma unroll
            for (int r = 0; r < 16; r++) {
                bool inc = !(wave == 1 && mt == 1) || (g == 0 && r < 4);
                if (inc) {
                    mx0 = fmaxf(mx0, (mt == 0) ? acc00[r] : acc10[r]);
                    mx1 = fmaxf(mx1, (mt == 0) ? acc01[r] : acc11[r]);
                }
            }
        }
        mx0 += bv0;
        mx1 += bv1;
    } else {
        unsigned wm0 = vb32[wave * 2];
        unsigned wm1 = vb32[wave * 2 + 1];
#pragma unroll
        for (int mt = 0; mt < 2; mt++) {
            unsigned wm = (mt == 0) ? wm0 : wm1;
#pragma unroll
            for (int r = 0; r < 16; r++) {
                int idx = (r & 3) + 8 * (r >> 2) + 4 * g;
                bool inc = !(wave == 1 && mt == 1) || (idx < 4);
                if (inc) {
                    bool vbit = (wm >> idx) & 1;
                    float a0 = (mt == 0) ? acc00[r] : acc10[r];
                    float a1 = (mt == 0) ? acc01[r] : acc11[r];
                    mx0 = fmaxf(mx0, vbit ? (a0 + bv0) : 0.0f);
                    mx1 = fmaxf(mx1, vbit ? (a1 + bv1) : 0.0f);
                }
            }
        }
    }
    mx0 = fmaxf(mx0, __shfl_xor(mx0, 32, 64));
    mx1 = fmaxf(mx1, __shfl_xor(mx1, 32, 64));
    if (lane < 32) { red[wave][mr] = mx0; red[wave][32 + mr] = mx1; }
    __syncthreads();
    if (n < F)
        pmax[(size_t)bp * F + n] = fmaxf(red[0][n], red[1][n]);
}

// ---------------------------------------------------------------------------
// Scatter: numpy last-write-wins via atomicMax(p) + conditional write.
// ---------------------------------------------------------------------------
__global__ __launch_bounds__(256) void winner_kernel(
    const int* __restrict__ idxs, int* __restrict__ winner)
{
    int i = blockIdx.x * 256 + threadIdx.x;
    if (i >= B * P) return;
    int ix = idxs[i * 2], iy = idxs[i * 2 + 1];
    int b = i / P, p = i % P;
    atomicMax(&winner[(b * NX + ix) * NY + iy], p);
}

__global__ __launch_bounds__(64) void scatter_kernel(
    const int* __restrict__ idxs, const int* __restrict__ winner,
    const float* __restrict__ pmax, __hip_bfloat16* __restrict__ img)
{
    int bp = blockIdx.x;
    int f = threadIdx.x;
    int ix = idxs[bp * 2], iy = idxs[bp * 2 + 1];
    int b = bp / P, p = bp % P;
    int cell = (b * NX + ix) * NY + iy;
    if (winner[cell] == p)
        img[(size_t)cell * F + f] = __float2bfloat16(pmax[(size_t)bp * F + f]);
}

// ---------------------------------------------------------------------------
// Weight converts. Conv weights -> [tap][ci/16][128 co][16 ci] bf16.
// ---------------------------------------------------------------------------
__global__ __launch_bounds__(256) void cvt_w_kernel(
    const float* __restrict__ w, __hip_bfloat16* __restrict__ wt, int cin)
{
    int idx = blockIdx.x * 256 + threadIdx.x;
    int total = 9 * cin * 128;
    if (idx >= total) return;
    int co = idx % 128;
    int rest = idx / 128;
    int ci = rest % cin;
    int t  = rest / cin;
    int c0 = ci >> 4, c16 = ci & 15;
    wt[(((size_t)(t * (cin >> 4) + c0)) * 128 + co) * 16 + c16] = __float2bfloat16(w[idx]);
}

__global__ __launch_bounds__(256) void cvt_w1_kernel(
    const float* __restrict__ w1, __hip_bfloat16* __restrict__ w1t)
{
    int idx = blockIdx.x * 256 + threadIdx.x;
    if (idx >= F * F) return;
    int k = idx >> 6, nn = idx & 63;
    w1t[nn * F + k] = __float2bfloat16(w1[idx]);
}

// w0 [8,64] fp32 -> w0p [4 slots][64 n][8 j] bf16 bits.
__global__ __launch_bounds__(256) void cvt_w0p_kernel(
    const float* __restrict__ w0, short* __restrict__ w0p)
{
    int idx = blockIdx.x * 256 + threadIdx.x;
    if (idx >= 4 * 64 * 8) return;
    int j = idx & 7;
    int nn = (idx >> 3) & 63;
    int s = idx >> 9;
    float wv = w0[j * F + nn];
    __hip_bfloat16 hb = __float2bfloat16(wv);
    short out = 0;
    if (s < 2)      out = (short)__bfloat16_as_ushort(hb);
    else if (s == 2) out = bf16_bits(wv - __bfloat162float(hb));
    w0p[idx] = out;
}

// ---------------------------------------------------------------------------
// MFMA implicit-GEMM 3x3 conv, SAME, Cout=128.  m97-style staging:
// LDS layout TRANSPOSED [cc][row]: column cc (8 per 64-ci pass) holds 16B
// granules, one per patch row (row = dx*64 + dy, dx in 0..3, dy in 0..63).
// Staged with global_load_lds width=16: wave-uniform LDS base + lane*16 =
// one 64-row column chunk; per-lane global ptrs (OOB lanes -> zerobuf).
// K-loop reads: lane mr -> consecutive granules = conflict-free b128.
// Block: 256 thr = 4 waves = 2 xr x 2 coh; tile 2x x 62y x 128co.
// Wave: 2M x 2N = 64 AGPR + ~80 VGPR -> 3 waves/SIMD; LDS 34.8KB -> 3 blk/CU.
// y0 in {0,62,124,178}; C-rows 62,63 are junk (read stale-but-finite LDS),
// masked at store (MFMA C rows independent).
// ---------------------------------------------------------------------------
template<int CIN, bool FUSE>
__global__ __launch_bounds__(256, 3) void conv_mfma(
    const __hip_bfloat16* __restrict__ in,    // [B,240,240,CIN] bf16
    const __hip_bfloat16* __restrict__ wt,    // [9][CIN/16][128][16] bf16
    const float* __restrict__ bias,           // [128]
    const float* __restrict__ w2,             // [128] (FUSE)
    const float* __restrict__ b2,             // [1]   (FUSE)
    const __hip_bfloat16* __restrict__ zerobuf, // >=16B of zeros
    __hip_bfloat16* __restrict__ out_bf,
    float* __restrict__ out_f)
{
    constexpr int PASSES = CIN / 64;
    constexpr int CI   = 64;              // ci per pass
    constexpr int NC16 = CI / 16;         // 4
    constexpr int CSTR = 272;             // column stride in granules (256 used + guard)
    __shared__ short sP[8 * CSTR * 8];    // 34,816 B
    __shared__ float sred[FUSE ? 2 : 1][2][64];

    int tid  = threadIdx.x;
    int wave = tid >> 6;
    int lane = tid & 63;
    int mr = lane & 31;
    int g  = lane >> 5;
    int coh = wave & 1;        // cout half
    int xr  = wave >> 1;       // output x-row within pair
    int x0 = blockIdx.x * 2;
    int y0 = blockIdx.y * 62;  // 0,62,124,186->178 (overlap benign)
    if (y0 > 178) y0 = 178;
    int b  = blockIdx.z;
    int n0 = coh * 64;

    const short* wts = (const short*)wt;

    f32x16 acc[2][2];
#pragma unroll
    for (int mt = 0; mt < 2; mt++)
#pragma unroll
        for (int nt = 0; nt < 2; nt++)
            acc[mt][nt] = (f32x16){0,0,0,0,0,0,0,0,0,0,0,0,0,0,0,0};

#pragma unroll
    for (int p = 0; p < PASSES; p++) {
        if (p) __syncthreads();

        // ---- stage pass p via global_load_lds: 32 (cc,dx) chunks, 8/wave ----
        {
            int gy = y0 - 1 + lane;              // dy = lane, 0..63
            bool yok = (gy >= 0 && gy < NY);
#pragma unroll
            for (int j = 0; j < 8; j++) {
                int q  = j * 4 + wave;           // 0..31
                int cc = q >> 2;                 // ci granule 0..7
                int dx = q & 3;                  // staged x-row 0..3
                int gx = x0 - 1 + dx;
                const __hip_bfloat16* src =
                    (yok && gx >= 0 && gx < NX)
                    ? &in[(((size_t)b * NX + gx) * NY + gy) * CIN + p * CI + cc * 8]
                    : zerobuf;
                async_load16(src, (void*)(sP + (cc * CSTR + dx * 64) * 8));
            }
        }
        __syncthreads();   // drains vmcnt (async LDS writes complete)

        // ---- K-loop: 9 taps, weights streamed from L2 at use ----
#pragma unroll
        for (int tap = 0; tap < 9; tap++) {
            int kh = tap / 3, kw = tap % 3;
            int rowcol = (xr + kh) * 64 + kw;
            const short* wrow = wts + ((size_t)(tap * (CIN / 16) + p * NC16) * 128 + n0 + mr) * 16 + g * 8;
#pragma unroll
            for (int c0 = 0; c0 < NC16; c0++) {
                short8 w0f = *(const short8*)(wrow + (size_t)c0 * 2048);
                short8 w1f = *(const short8*)(wrow + (size_t)c0 * 2048 + 512);
                int cc = c0 * 2 + g;
                const short* abase = sP + (cc * CSTR + rowcol + mr) * 8;
                short8 a0 = *(const short8*)(abase);
                short8 a1 = *(const short8*)(abase + 32 * 8);   // +32 rows
                acc[0][0] = __builtin_amdgcn_mfma_f32_32x32x16_bf16(a0, w0f, acc[0][0], 0, 0, 0);
                acc[0][1] = __builtin_amdgcn_mfma_f32_32x32x16_bf16(a0, w1f, acc[0][1], 0, 0, 0);
                acc[1][0] = __builtin_amdgcn_mfma_f32_32x32x16_bf16(a1, w0f, acc[1][0], 0, 0, 0);
                acc[1][1] = __builtin_amdgcn_mfma_f32_32x32x16_bf16(a1, w1f, acc[1][1], 0, 0, 0);
            }
        }
    }

    // ---- epilogue (C-rows >= 62 are junk: masked) ----
    float bv0 = bias[n0 + mr];
    float bv1 = bias[n0 + 32 + mr];
    if (!FUSE) {
        size_t base = ((size_t)b * NX + (x0 + xr)) * NY;
#pragma unroll
        for (int mt = 0; mt < 2; mt++) {
#pragma unroll
            for (int r = 0; r < 16; r++) {
                int row = mt * 32 + (r & 3) + 8 * (r >> 2) + 4 * g;
                if (row < 62) {
                    int y = y0 + row;
                    out_bf[(base + y) * C1 + n0 + mr]      = __float2bfloat16(tanh_fast(acc[mt][0][r] + bv0));
                    out_bf[(base + y) * C1 + n0 + 32 + mr] = __float2bfloat16(tanh_fast(acc[mt][1][r] + bv1));
                }
            }
        }
    } else {
        float w20 = w2[n0 + mr];
        float w21 = w2[n0 + 32 + mr];
#pragma unroll
        for (int mt = 0; mt < 2; mt++) {
#pragma unroll
            for (int r = 0; r < 16; r++) {
                float v = tanh_fast(acc[mt][0][r] + bv0) * w20
                        + tanh_fast(acc[mt][1][r] + bv1) * w21;
                v += __shfl_xor(v, 1, 64);
                v += __shfl_xor(v, 2, 64);
                v += __shfl_xor(v, 4, 64);
                v += __shfl_xor(v, 8, 64);
                v += __shfl_xor(v, 16, 64);
                if (mr == 0)
                    sred[coh][xr][mt * 32 + (r & 3) + 8 * (r >> 2) + 4 * g] = v;
            }
        }
        __syncthreads();
        if (tid < 128) {
            int xr2 = tid >> 6;
            int yy  = tid & 63;
            if (yy < 62) {
                float r = sred[0][xr2][yy] + sred[1][xr2][yy] + b2[0];
                out_f[((size_t)b * NX + (x0 + xr2)) * NY + (y0 + yy)] = fmaxf(r, 0.f);
            }
        }
    }
}

// ---------------------------------------------------------------------------
extern "C" void kernel_launch(void* const* d_in, const int* in_sizes, int n_in,
                              void* d_out, int out_size, void* d_ws, size_t ws_size,
                              hipStream_t stream) {
    const float* pillars = (const float*)d_in[0];
    const int*   idxs    = (const int*)d_in[1];
    const float* pn_w0   = (const float*)d_in[4];
    const float* pn_b0   = (const float*)d_in[5];
    const float* pn_w1   = (const float*)d_in[6];
    const float* pn_b1   = (const float*)d_in[7];
    const float* cw0     = (const float*)d_in[8];
    const float* cb0     = (const float*)d_in[9];
    const float* cw1     = (const float*)d_in[10];
    const float* cb1     = (const float*)d_in[11];
    const float* cw2     = (const float*)d_in[12];
    const float* cb2     = (const float*)d_in[13];
    float* out = (float*)d_out;

    // workspace layout
    char* ws = (char*)d_ws;
    const size_t IMG_BYTES  = (size_t)B * NX * NY * F * 2;
    const size_t OUT1_BYTES = (size_t)B * NX * NY * C1 * 2;
    const size_t WIN_BYTES  = (size_t)B * NX * NY * 4;
    const size_t PMAX_BYTES = (size_t)B * P * F * 4;
    const size_t WT1_BYTES  = (size_t)9 * C1 * F * 2;
    const size_t WT2_BYTES  = (size_t)9 * C1 * C1 * 2;
    const size_t W1T_BYTES  = (size_t)F * F * 2;
    const size_t W0P_BYTES  = (size_t)4 * 64 * 8 * 2;
    __hip_bfloat16* img  = (__hip_bfloat16*)ws;
    __hip_bfloat16* out1 = (__hip_bfloat16*)(ws + IMG_BYTES);
    int*   winner = (int*)(ws + IMG_BYTES + OUT1_BYTES);
    float* pmax   = (float*)(ws + IMG_BYTES + OUT1_BYTES + WIN_BYTES);
    __hip_bfloat16* wt1 = (__hip_bfloat16*)(ws + IMG_BYTES + OUT1_BYTES + WIN_BYTES + PMAX_BYTES);
    __hip_bfloat16* wt2 = (__hip_bfloat16*)(ws + IMG_BYTES + OUT1_BYTES + WIN_BYTES + PMAX_BYTES + WT1_BYTES);
    __hip_bfloat16* w1t = (__hip_bfloat16*)(ws + IMG_BYTES + OUT1_BYTES + WIN_BYTES + PMAX_BYTES + WT1_BYTES + WT2_BYTES);
    short* w0p = (short*)(ws + IMG_BYTES + OUT1_BYTES + WIN_BYTES + PMAX_BYTES + WT1_BYTES + WT2_BYTES + W1T_BYTES);
    __hip_bfloat16* zerobuf = (__hip_bfloat16*)(ws + IMG_BYTES + OUT1_BYTES + WIN_BYTES + PMAX_BYTES + WT1_BYTES + WT2_BYTES + W1T_BYTES + W0P_BYTES);

    hipMemsetAsync(img, 0, IMG_BYTES, stream);
    hipMemsetAsync(winner, 0xFF, WIN_BYTES, stream);   // -1
    hipMemsetAsync(zerobuf, 0, 64, stream);            // OOB target for async staging

    cvt_w_kernel<<<(9 * F * C1 + 255) / 256, 256, 0, stream>>>(cw0, wt1, F);
    cvt_w_kernel<<<(9 * C1 * C1 + 255) / 256, 256, 0, stream>>>(cw1, wt2, C1);
    cvt_w1_kernel<<<(F * F + 255) / 256, 256, 0, stream>>>(pn_w1, w1t);
    cvt_w0p_kernel<<<(4 * 64 * 8 + 255) / 256, 256, 0, stream>>>(pn_w0, w0p);

    pn_mfma_kernel<<<B * P, 128, 0, stream>>>(pillars, w0p, pn_b0, w1t, pn_b1, pmax);
    winner_kernel<<<(B * P + 255) / 256, 256, 0, stream>>>(idxs, winner);
    scatter_kernel<<<B * P, 64, 0, stream>>>(idxs, winner, pmax, img);

    conv_mfma<F, false><<<dim3(NX / 2, 4, B), 256, 0, stream>>>(
        img, wt1, cb0, nullptr, nullptr, zerobuf, out1, nullptr);
    conv_mfma<C1, true><<<dim3(NX / 2, 4, B), 256, 0, stream>>>(
        out1, wt2, cb1, cw2, cb2, zerobuf, nullptr, out);
}

// Round 12
// 348.238 us; speedup vs baseline: 1.1105x; 1.0276x over previous
//
#include <hip/hip_runtime.h>
#include <hip/hip_bf16.h>
#include <math.h>

// Problem constants (fixed by setup_inputs)
#define B  4
#define P  5000
#define NPT 100
#define F  64          // pointnet feature dim
#define NX 240
#define NY 240
#define C1 128         // conv1/conv2 out channels

typedef __attribute__((ext_vector_type(8)))  short short8;   // 8 bf16
typedef __attribute__((ext_vector_type(16))) float f32x16;

// tanh via v_exp + v_rcp (rel err ~1e-6; saturates correctly at +-1)
__device__ __forceinline__ float tanh_fast(float x) {
    float e = exp2f(x * 2.8853900817779268f);   // 2*log2(e): single v_exp
    float r = __builtin_amdgcn_rcpf(e + 1.0f);
    return __builtin_fmaf(-2.0f, r, 1.0f);
}
__device__ __forceinline__ short bf16_bits(float f) {
    return (short)(__bfloat16_as_ushort(__float2bfloat16(f)));
}
// async 16B global->LDS: wave-uniform LDS base + lane*16
__device__ __forceinline__ void async_load16(const void* g, void* l) {
    __builtin_amdgcn_global_load_lds(
        (const __attribute__((address_space(1))) void*)g,
        (__attribute__((address_space(3))) void*)l, 16, 0, 0);
}

// ---------------------------------------------------------------------------
// PointNet, both layers on MFMA.
// Block = 1 pillar, 128 threads (2 waves); points 100..127 phantoms.
// R12: xA (stride-40 staging, 10KB) ALIASES hA (stride-72, 18.4KB) in one
// buffer -> LDS 29.7->19KB -> 8 blocks/CU = 4 waves/SIMD (was 2.5).
// Barrier after layer-1 MFMA guards the alias (xA reads before hA writes).
// ---------------------------------------------------------------------------
__global__ __launch_bounds__(128, 4) void pn_mfma_kernel(
    const float* __restrict__ pillars,    // [B,P,N,8]
    const short* __restrict__ w0p,        // [4 slots][64 n][8 k] bf16 bits
    const float* __restrict__ b0,         // [64]
    const __hip_bfloat16* __restrict__ w1t, // [64n][64k] bf16
    const float* __restrict__ b1,         // [64]
    float* __restrict__ pmax)             // [B*P,64]
{
    constexpr int HS = F + 8;             // 72 shorts
    constexpr int XS = 40;                // 80B row: bank stride 20 -> max 4-way
    __shared__ short buf[128 * HS];       // 18,432 B, aliased xA/hA
    __shared__ float red[2][F];
    __shared__ unsigned int vb32[4];
    short* xA = buf;                      // [128][40]
    short* hA = buf;                      // [128][72] (after alias barrier)

    int bp = blockIdx.x;
    int n  = threadIdx.x;
    int wave = n >> 6, lane = n & 63;
    int mr = lane & 31;
    int g  = lane >> 5;
    bool live = (n < NPT);

    const float* xp = pillars + ((size_t)bp * NPT + (live ? n : 0)) * 8;
    float4 q0 = *(const float4*)xp;
    float4 q1 = *(const float4*)(xp + 4);
    float x[8] = {q0.x, q0.y, q0.z, q0.w, q1.x, q1.y, q1.z, q1.w};

    float ss = 0.f;
#pragma unroll
    for (int c = 0; c < 8; c++) ss += x[c] * x[c];
    bool valid = live && (ss < 1e12f);

    unsigned long long bal = __ballot(valid);
    if (lane == 0) {
        vb32[wave * 2]     = (unsigned)bal;
        vb32[wave * 2 + 1] = (unsigned)(bal >> 32);
    }

    short8 xhi, xlo, xz;
#pragma unroll
    for (int c = 0; c < 8; c++) {
        __hip_bfloat16 hb = __float2bfloat16(x[c]);
        float hv = __bfloat162float(hb);
        xhi[c] = (short)__bfloat16_as_ushort(hb);
        xlo[c] = bf16_bits(x[c] - hv);
        xz[c] = 0;
    }
    *(short8*)&xA[n * XS + 0]  = xhi;
    *(short8*)&xA[n * XS + 8]  = xlo;
    *(short8*)&xA[n * XS + 16] = xhi;
    *(short8*)&xA[n * XS + 24] = xz;
    __syncthreads();

    short8 wb[2][2];   // [kk][nt]
#pragma unroll
    for (int kk = 0; kk < 2; kk++)
#pragma unroll
        for (int nt = 0; nt < 2; nt++)
            wb[kk][nt] = *(const short8*)(w0p + ((kk * 2 + g) * 64 + nt * 32 + mr) * 8);

    f32x16 hc00 = {0,0,0,0,0,0,0,0,0,0,0,0,0,0,0,0};
    f32x16 hc01 = hc00, hc10 = hc00, hc11 = hc00;
#pragma unroll
    for (int kk = 0; kk < 2; kk++) {
        short8 a0 = *(const short8*)&xA[(wave * 64 + mr) * XS + kk * 16 + g * 8];
        short8 a1 = *(const short8*)&xA[(wave * 64 + 32 + mr) * XS + kk * 16 + g * 8];
        hc00 = __builtin_amdgcn_mfma_f32_32x32x16_bf16(a0, wb[kk][0], hc00, 0, 0, 0);
        hc01 = __builtin_amdgcn_mfma_f32_32x32x16_bf16(a0, wb[kk][1], hc01, 0, 0, 0);
        hc10 = __builtin_amdgcn_mfma_f32_32x32x16_bf16(a1, wb[kk][0], hc10, 0, 0, 0);
        hc11 = __builtin_amdgcn_mfma_f32_32x32x16_bf16(a1, wb[kk][1], hc11, 0, 0, 0);
    }
    __syncthreads();   // ALIAS GUARD: all xA reads complete before hA writes

    float b00 = b0[mr];
    float b01 = b0[32 + mr];
#pragma unroll
    for (int mt = 0; mt < 2; mt++) {
#pragma unroll
        for (int r = 0; r < 16; r++) {
            int prow = wave * 64 + mt * 32 + (r & 3) + 8 * (r >> 2) + 4 * g;
            float h0 = (mt == 0) ? hc00[r] : hc10[r];
            float h1 = (mt == 0) ? hc01[r] : hc11[r];
            hA[prow * HS + mr]      = bf16_bits(tanh_fast(h0 + b00));
            hA[prow * HS + 32 + mr] = bf16_bits(tanh_fast(h1 + b01));
        }
    }
    __syncthreads();

    short8 bfrag[2][4];
#pragma unroll
    for (int nt = 0; nt < 2; nt++)
#pragma unroll
        for (int c0 = 0; c0 < 4; c0++)
            bfrag[nt][c0] = *(const short8*)((const short*)w1t +
                                (nt * 32 + mr) * F + c0 * 16 + g * 8);

    f32x16 acc00 = {0,0,0,0,0,0,0,0,0,0,0,0,0,0,0,0};
    f32x16 acc01 = acc00, acc10 = acc00, acc11 = acc00;

    const short* arow = &hA[(wave * 64 + mr) * HS + g * 8];
#pragma unroll
    for (int c0 = 0; c0 < 4; c0++) {
        short8 af0 = *(const short8*)(arow + c0 * 16);
        short8 af1 = *(const short8*)(arow + 32 * HS + c0 * 16);
        acc00 = __builtin_amdgcn_mfma_f32_32x32x16_bf16(af0, bfrag[0][c0], acc00, 0, 0, 0);
        acc01 = __builtin_amdgcn_mfma_f32_32x32x16_bf16(af0, bfrag[1][c0], acc01, 0, 0, 0);
        acc10 = __builtin_amdgcn_mfma_f32_32x32x16_bf16(af1, bfrag[0][c0], acc10, 0, 0, 0);
        acc11 = __builtin_amdgcn_mfma_f32_32x32x16_bf16(af1, bfrag[1][c0], acc11, 0, 0, 0);
    }

    float bv0 = b1[mr];
    float bv1 = b1[32 + mr];
    bool allv = ((vb32[0] & vb32[1] & vb32[2]) == 0xFFFFFFFFu) &&
                ((vb32[3] & 0xFu) == 0xFu);
    float mx0 = -INFINITY, mx1 = -INFINITY;

    if (allv) {
#pragma unroll
        for (int mt = 0; mt < 2; mt++) {
#pragma unroll
            for (int r = 0; r < 16; r++) {
                bool inc = !(wave == 1 && mt == 1) || (g == 0 && r < 4);
                if (inc) {
                    mx0 = fmaxf(mx0, (mt == 0) ? acc00[r] : acc10[r]);
                    mx1 = fmaxf(mx1, (mt == 0) ? acc01[r] : acc11[r]);
                }
            }
        }
        mx0 += bv0;
        mx1 += bv1;
    } else {
        unsigned wm0 = vb32[wave * 2];
        unsigned wm1 = vb32[wave * 2 + 1];
#pragma unroll
        for (int mt = 0; mt < 2; mt++) {
            unsigned wm = (mt == 0) ? wm0 : wm1;
#pragma unroll
            for (int r = 0; r < 16; r++) {
                int idx = (r & 3) + 8 * (r >> 2) + 4 * g;
                bool inc = !(wave == 1 && mt == 1) || (idx < 4);
                if (inc) {
                    bool vbit = (wm >> idx) & 1;
                    float a0 = (mt == 0) ? acc00[r] : acc10[r];
                    float a1 = (mt == 0) ? acc01[r] : acc11[r];
                    mx0 = fmaxf(mx0, vbit ? (a0 + bv0) : 0.0f);
                    mx1 = fmaxf(mx1, vbit ? (a1 + bv1) : 0.0f);
                }
            }
        }
    }
    mx0 = fmaxf(mx0, __shfl_xor(mx0, 32, 64));
    mx1 = fmaxf(mx1, __shfl_xor(mx1, 32, 64));
    if (lane < 32) { red[wave][mr] = mx0; red[wave][32 + mr] = mx1; }
    __syncthreads();
    if (n < F)
        pmax[(size_t)bp * F + n] = fmaxf(red[0][n], red[1][n]);
}

// ---------------------------------------------------------------------------
// Scatter: numpy last-write-wins via atomicMax(p) + conditional write.
// ---------------------------------------------------------------------------
__global__ __launch_bounds__(256) void winner_kernel(
    const int* __restrict__ idxs, int* __restrict__ winner)
{
    int i = blockIdx.x * 256 + threadIdx.x;
    if (i >= B * P) return;
    int ix = idxs[i * 2], iy = idxs[i * 2 + 1];
    int b = i / P, p = i % P;
    atomicMax(&winner[(b * NX + ix) * NY + iy], p);
}

__global__ __launch_bounds__(64) void scatter_kernel(
    const int* __restrict__ idxs, const int* __restrict__ winner,
    const float* __restrict__ pmax, __hip_bfloat16* __restrict__ img)
{
    int bp = blockIdx.x;
    int f = threadIdx.x;
    int ix = idxs[bp * 2], iy = idxs[bp * 2 + 1];
    int b = bp / P, p = bp % P;
    int cell = (b * NX + ix) * NY + iy;
    if (winner[cell] == p)
        img[(size_t)cell * F + f] = __float2bfloat16(pmax[(size_t)bp * F + f]);
}

// ---------------------------------------------------------------------------
// Weight converts. Conv weights -> [tap][ci/16][128 co][16 ci] bf16.
// ---------------------------------------------------------------------------
__global__ __launch_bounds__(256) void cvt_w_kernel(
    const float* __restrict__ w, __hip_bfloat16* __restrict__ wt, int cin)
{
    int idx = blockIdx.x * 256 + threadIdx.x;
    int total = 9 * cin * 128;
    if (idx >= total) return;
    int co = idx % 128;
    int rest = idx / 128;
    int ci = rest % cin;
    int t  = rest / cin;
    int c0 = ci >> 4, c16 = ci & 15;
    wt[(((size_t)(t * (cin >> 4) + c0)) * 128 + co) * 16 + c16] = __float2bfloat16(w[idx]);
}

__global__ __launch_bounds__(256) void cvt_w1_kernel(
    const float* __restrict__ w1, __hip_bfloat16* __restrict__ w1t)
{
    int idx = blockIdx.x * 256 + threadIdx.x;
    if (idx >= F * F) return;
    int k = idx >> 6, nn = idx & 63;
    w1t[nn * F + k] = __float2bfloat16(w1[idx]);
}

// w0 [8,64] fp32 -> w0p [4 slots][64 n][8 j] bf16 bits.
__global__ __launch_bounds__(256) void cvt_w0p_kernel(
    const float* __restrict__ w0, short* __restrict__ w0p)
{
    int idx = blockIdx.x * 256 + threadIdx.x;
    if (idx >= 4 * 64 * 8) return;
    int j = idx & 7;
    int nn = (idx >> 3) & 63;
    int s = idx >> 9;
    float wv = w0[j * F + nn];
    __hip_bfloat16 hb = __float2bfloat16(wv);
    short out = 0;
    if (s < 2)      out = (short)__bfloat16_as_ushort(hb);
    else if (s == 2) out = bf16_bits(wv - __bfloat162float(hb));
    w0p[idx] = out;
}

// ---------------------------------------------------------------------------
// MFMA implicit-GEMM 3x3 conv, SAME, Cout=128 (unchanged from R11).
// Transposed LDS [cc][row] + global_load_lds width=16 staging; 0 conflicts.
// ---------------------------------------------------------------------------
template<int CIN, bool FUSE>
__global__ __launch_bounds__(256, 3) void conv_mfma(
    const __hip_bfloat16* __restrict__ in,    // [B,240,240,CIN] bf16
    const __hip_bfloat16* __restrict__ wt,    // [9][CIN/16][128][16] bf16
    const float* __restrict__ bias,           // [128]
    const float* __restrict__ w2,             // [128] (FUSE)
    const float* __restrict__ b2,             // [1]   (FUSE)
    const __hip_bfloat16* __restrict__ zerobuf, // >=16B of zeros
    __hip_bfloat16* __restrict__ out_bf,
    float* __restrict__ out_f)
{
    constexpr int PASSES = CIN / 64;
    constexpr int CI   = 64;              // ci per pass
    constexpr int NC16 = CI / 16;         // 4
    constexpr int CSTR = 272;             // column stride in granules
    __shared__ short sP[8 * CSTR * 8];    // 34,816 B
    __shared__ float sred[FUSE ? 2 : 1][2][64];

    int tid  = threadIdx.x;
    int wave = tid >> 6;
    int lane = tid & 63;
    int mr = lane & 31;
    int g  = lane >> 5;
    int coh = wave & 1;        // cout half
    int xr  = wave >> 1;       // output x-row within pair
    int x0 = blockIdx.x * 2;
    int y0 = blockIdx.y * 62;  // 0,62,124,186->178 (overlap benign)
    if (y0 > 178) y0 = 178;
    int b  = blockIdx.z;
    int n0 = coh * 64;

    const short* wts = (const short*)wt;

    f32x16 acc[2][2];
#pragma unroll
    for (int mt = 0; mt < 2; mt++)
#pragma unroll
        for (int nt = 0; nt < 2; nt++)
            acc[mt][nt] = (f32x16){0,0,0,0,0,0,0,0,0,0,0,0,0,0,0,0};

#pragma unroll
    for (int p = 0; p < PASSES; p++) {
        if (p) __syncthreads();

        // ---- stage pass p via global_load_lds: 32 (cc,dx) chunks, 8/wave ----
        {
            int gy = y0 - 1 + lane;              // dy = lane, 0..63
            bool yok = (gy >= 0 && gy < NY);
#pragma unroll
            for (int j = 0; j < 8; j++) {
                int q  = j * 4 + wave;           // 0..31
                int cc = q >> 2;                 // ci granule 0..7
                int dx = q & 3;                  // staged x-row 0..3
                int gx = x0 - 1 + dx;
                const __hip_bfloat16* src =
                    (yok && gx >= 0 && gx < NX)
                    ? &in[(((size_t)b * NX + gx) * NY + gy) * CIN + p * CI + cc * 8]
                    : zerobuf;
                async_load16(src, (void*)(sP + (cc * CSTR + dx * 64) * 8));
            }
        }
        __syncthreads();   // drains vmcnt (async LDS writes complete)

        // ---- K-loop: 9 taps, weights streamed from L2 at use ----
#pragma unroll
        for (int tap = 0; tap < 9; tap++) {
            int kh = tap / 3, kw = tap % 3;
            int rowcol = (xr + kh) * 64 + kw;
            const short* wrow = wts + ((size_t)(tap * (CIN / 16) + p * NC16) * 128 + n0 + mr) * 16 + g * 8;
#pragma unroll
            for (int c0 = 0; c0 < NC16; c0++) {
                short8 w0f = *(const short8*)(wrow + (size_t)c0 * 2048);
                short8 w1f = *(const short8*)(wrow + (size_t)c0 * 2048 + 512);
                int cc = c0 * 2 + g;
                const short* abase = sP + (cc * CSTR + rowcol + mr) * 8;
                short8 a0 = *(const short8*)(abase);
                short8 a1 = *(const short8*)(abase + 32 * 8);   // +32 rows
                acc[0][0] = __builtin_amdgcn_mfma_f32_32x32x16_bf16(a0, w0f, acc[0][0], 0, 0, 0);
                acc[0][1] = __builtin_amdgcn_mfma_f32_32x32x16_bf16(a0, w1f, acc[0][1], 0, 0, 0);
                acc[1][0] = __builtin_amdgcn_mfma_f32_32x32x16_bf16(a1, w0f, acc[1][0], 0, 0, 0);
                acc[1][1] = __builtin_amdgcn_mfma_f32_32x32x16_bf16(a1, w1f, acc[1][1], 0, 0, 0);
            }
        }
    }

    // ---- epilogue (C-rows >= 62 are junk: masked) ----
    float bv0 = bias[n0 + mr];
    float bv1 = bias[n0 + 32 + mr];
    if (!FUSE) {
        size_t base = ((size_t)b * NX + (x0 + xr)) * NY;
#pragma unroll
        for (int mt = 0; mt < 2; mt++) {
#pragma unroll
            for (int r = 0; r < 16; r++) {
                int row = mt * 32 + (r & 3) + 8 * (r >> 2) + 4 * g;
                if (row < 62) {
                    int y = y0 + row;
                    out_bf[(base + y) * C1 + n0 + mr]      = __float2bfloat16(tanh_fast(acc[mt][0][r] + bv0));
                    out_bf[(base + y) * C1 + n0 + 32 + mr] = __float2bfloat16(tanh_fast(acc[mt][1][r] + bv1));
                }
            }
        }
    } else {
        float w20 = w2[n0 + mr];
        float w21 = w2[n0 + 32 + mr];
#pragma unroll
        for (int mt = 0; mt < 2; mt++) {
#pragma unroll
            for (int r = 0; r < 16; r++) {
                float v = tanh_fast(acc[mt][0][r] + bv0) * w20
                        + tanh_fast(acc[mt][1][r] + bv1) * w21;
                v += __shfl_xor(v, 1, 64);
                v += __shfl_xor(v, 2, 64);
                v += __shfl_xor(v, 4, 64);
                v += __shfl_xor(v, 8, 64);
                v += __shfl_xor(v, 16, 64);
                if (mr == 0)
                    sred[coh][xr][mt * 32 + (r & 3) + 8 * (r >> 2) + 4 * g] = v;
            }
        }
        __syncthreads();
        if (tid < 128) {
            int xr2 = tid >> 6;
            int yy  = tid & 63;
            if (yy < 62) {
                float r = sred[0][xr2][yy] + sred[1][xr2][yy] + b2[0];
                out_f[((size_t)b * NX + (x0 + xr2)) * NY + (y0 + yy)] = fmaxf(r, 0.f);
            }
        }
    }
}

// ---------------------------------------------------------------------------
extern "C" void kernel_launch(void* const* d_in, const int* in_sizes, int n_in,
                              void* d_out, int out_size, void* d_ws, size_t ws_size,
                              hipStream_t stream) {
    const float* pillars = (const float*)d_in[0];
    const int*   idxs    = (const int*)d_in[1];
    const float* pn_w0   = (const float*)d_in[4];
    const float* pn_b0   = (const float*)d_in[5];
    const float* pn_w1   = (const float*)d_in[6];
    const float* pn_b1   = (const float*)d_in[7];
    const float* cw0     = (const float*)d_in[8];
    const float* cb0     = (const float*)d_in[9];
    const float* cw1     = (const float*)d_in[10];
    const float* cb1     = (const float*)d_in[11];
    const float* cw2     = (const float*)d_in[12];
    const float* cb2     = (const float*)d_in[13];
    float* out = (float*)d_out;

    // workspace layout
    char* ws = (char*)d_ws;
    const size_t IMG_BYTES  = (size_t)B * NX * NY * F * 2;
    const size_t OUT1_BYTES = (size_t)B * NX * NY * C1 * 2;
    const size_t WIN_BYTES  = (size_t)B * NX * NY * 4;
    const size_t PMAX_BYTES = (size_t)B * P * F * 4;
    const size_t WT1_BYTES  = (size_t)9 * C1 * F * 2;
    const size_t WT2_BYTES  = (size_t)9 * C1 * C1 * 2;
    const size_t W1T_BYTES  = (size_t)F * F * 2;
    const size_t W0P_BYTES  = (size_t)4 * 64 * 8 * 2;
    __hip_bfloat16* img  = (__hip_bfloat16*)ws;
    __hip_bfloat16* out1 = (__hip_bfloat16*)(ws + IMG_BYTES);
    int*   winner = (int*)(ws + IMG_BYTES + OUT1_BYTES);
    float* pmax   = (float*)(ws + IMG_BYTES + OUT1_BYTES + WIN_BYTES);
    __hip_bfloat16* wt1 = (__hip_bfloat16*)(ws + IMG_BYTES + OUT1_BYTES + WIN_BYTES + PMAX_BYTES);
    __hip_bfloat16* wt2 = (__hip_bfloat16*)(ws + IMG_BYTES + OUT1_BYTES + WIN_BYTES + PMAX_BYTES + WT1_BYTES);
    __hip_bfloat16* w1t = (__hip_bfloat16*)(ws + IMG_BYTES + OUT1_BYTES + WIN_BYTES + PMAX_BYTES + WT1_BYTES + WT2_BYTES);
    short* w0p = (short*)(ws + IMG_BYTES + OUT1_BYTES + WIN_BYTES + PMAX_BYTES + WT1_BYTES + WT2_BYTES + W1T_BYTES);
    __hip_bfloat16* zerobuf = (__hip_bfloat16*)(ws + IMG_BYTES + OUT1_BYTES + WIN_BYTES + PMAX_BYTES + WT1_BYTES + WT2_BYTES + W1T_BYTES + W0P_BYTES);

    hipMemsetAsync(img, 0, IMG_BYTES, stream);
    hipMemsetAsync(winner, 0xFF, WIN_BYTES, stream);   // -1
    hipMemsetAsync(zerobuf, 0, 64, stream);            // OOB target for async staging

    cvt_w_kernel<<<(9 * F * C1 + 255) / 256, 256, 0, stream>>>(cw0, wt1, F);
    cvt_w_kernel<<<(9 * C1 * C1 + 255) / 256, 256, 0, stream>>>(cw1, wt2, C1);
    cvt_w1_kernel<<<(F * F + 255) / 256, 256, 0, stream>>>(pn_w1, w1t);
    cvt_w0p_kernel<<<(4 * 64 * 8 + 255) / 256, 256, 0, stream>>>(pn_w0, w0p);

    pn_mfma_kernel<<<B * P, 128, 0, stream>>>(pillars, w0p, pn_b0, w1t, pn_b1, pmax);
    winner_kernel<<<(B * P + 255) / 256, 256, 0, stream>>>(idxs, winner);
    scatter_kernel<<<B * P, 64, 0, stream>>>(idxs, winner, pmax, img);

    conv_mfma<F, false><<<dim3(NX / 2, 4, B), 256, 0, stream>>>(
        img, wt1, cb0, nullptr, nullptr, zerobuf, out1, nullptr);
    conv_mfma<C1, true><<<dim3(NX / 2, 4, B), 256, 0, stream>>>(
        out1, wt2, cb1, cw2, cb2, zerobuf, nullptr, out);
}